// Round 11
// baseline (475.763 us; speedup 1.0000x reference)
//
#include <hip/hip_runtime.h>

typedef unsigned short u16;
typedef __bf16 bf16x8 __attribute__((ext_vector_type(8)));
typedef float f32x4 __attribute__((ext_vector_type(4)));
typedef u16 u16x4 __attribute__((ext_vector_type(4)));

#define S_ 2048

__device__ __forceinline__ u16 f2bf(float f) {
  union { float f; unsigned u; } v; v.f = f;
  unsigned r = v.u + 0x7fffu + ((v.u >> 16) & 1u);
  return (u16)(r >> 16);
}

__device__ __forceinline__ f32x4 mfma16(bf16x8 a, bf16x8 b, f32x4 c) {
  return __builtin_amdgcn_mfma_f32_16x16x32_bf16(a, b, c, 0, 0, 0);
}

__device__ __forceinline__ void async16(const void* g, void* l) {
  __builtin_amdgcn_global_load_lds((__attribute__((address_space(1))) void*)g,
                                   (__attribute__((address_space(3))) void*)l,
                                   16, 0, 0);
}

// 1/sqrt(192) * log2(e): folded into q_b output so attn softmax is 2^s
// (single v_exp_f32 via __builtin_amdgcn_exp2f; libm exp2f was R7's regression)
#define QSCALE2 0.10411756755f

// ---------------- fused prep: hs cast (blk<4096) + 5 weight transposes --------
__global__ __launch_bounds__(256)
void prep_k(const float* __restrict__ hs, u16* __restrict__ hs_bf,
            const float* __restrict__ q_a_w, const float* __restrict__ kv_a_w,
            const float* __restrict__ q_b_w, const float* __restrict__ kv_b_w,
            const float* __restrict__ o_w,
            u16* __restrict__ qakvT, u16* __restrict__ qbwT,
            u16* __restrict__ kvbwT, u16* __restrict__ owT) {
  int blk = blockIdx.x;
  int tid = threadIdx.x;
  if (blk < 4096) {
    int i = blk * 256 + tid;
    f32x4 a = ((const f32x4*)hs)[2 * i], b = ((const f32x4*)hs)[2 * i + 1];
    union { u16 v[8]; f32x4 q; } u;
#pragma unroll
    for (int e = 0; e < 4; ++e) { u.v[e] = f2bf(a[e]); u.v[4 + e] = f2bf(b[e]); }
    ((f32x4*)hs_bf)[i] = u.q;
    return;
  }
  blk -= 4096;
  const float* W; u16* Wt; int K, N, gx;
  if (blk < 3072)       { W = q_a_w;  Wt = qakvT;                     K = 2048; N = 1536; gx = 64; }
  else if (blk < 4352)  { blk -= 3072;  W = kv_a_w; Wt = qakvT + (long)1536 * 2048; K = 2048; N = 576;  gx = 64; }
  else if (blk < 8960)  { blk -= 4352;  W = q_b_w;  Wt = qbwT;  K = 1536; N = 3072; gx = 48; }
  else if (blk < 11008) { blk -= 8960;  W = kv_b_w; Wt = kvbwT; K = 512;  N = 4096; gx = 16; }
  else                  { blk -= 11008; W = o_w;    Wt = owT;   K = 2048; N = 2048; gx = 64; }
  int k0 = (blk % gx) * 32, n0 = (blk / gx) * 32;
  int tx = tid & 31, ty = tid >> 5;
  __shared__ float tile[32][33];
#pragma unroll
  for (int r = 0; r < 32; r += 8) {
    int n = n0 + tx;
    tile[ty + r][tx] = (n < N) ? W[(long)(k0 + ty + r) * N + n] : 0.f;
  }
  __syncthreads();
#pragma unroll
  for (int r = 0; r < 32; r += 8) {
    Wt[(long)(n0 + ty + r) * K + k0 + tx] = f2bf(tile[tx][ty + r]);
  }
}

// XCD-chunked bijective block remap (T1): wgid%8 selects the XCD.
__device__ __forceinline__ int xcd_chunk(int lin, int nwg) {
  if ((nwg & 7) == 0) return (lin & 7) * (nwg >> 3) + (lin >> 3);
  return lin;
}

// ---------------- C[M,N] = A[M,K] @ Bt[N,K]^T, optional fused RoPE epilogue ---
// 128x128 tile, BK=64 (2x compute per sync amortizes the staging drain;
// half the barriers). Double-buffered issue-early/drain-at-sync pipeline.
// 8-slot XOR swizzle (R6-verified): chunk kc of row r stored at slot
// kc ^ (r&7); stage keeps LDS dest linear and permutes the GLOBAL source
// within each row's 128B segment; read slot = (ks*4+quad) ^ (row&7)
// -> 16 lanes spread over 8 slots = 2 lanes/slot = conflict-free.
template <typename OUT_T, bool ROPE>
__global__ __launch_bounds__(256)
void gemm_bt_k(const u16* __restrict__ A, const u16* __restrict__ Bt,
               OUT_T* __restrict__ C, int K, int Nc, int ldc,
               const float* __restrict__ cs, const float* __restrict__ sn) {
  __shared__ __align__(16) u16 sA[2][128 * 64];
  __shared__ __align__(16) u16 sB[2][128 * 64];
  int tid = threadIdx.x;
  int lane = tid & 63, w = tid >> 6;
  int wr = w >> 1, wc = w & 1;
  int l15 = lane & 15, quad = lane >> 4;
  int gx = gridDim.x;
  int nl = xcd_chunk(blockIdx.x + gx * blockIdx.y, gx * gridDim.y);
  long tm = (long)(nl / gx) * 128;
  long tn = (long)(nl % gx) * 128;
  const u16* Ab = A + tm * K;
  const u16* Bb = Bt + tn * K;
  f32x4 acc[4][4] = {};

#pragma unroll
  for (int it = 0; it < 4; ++it) {
    int c = tid + it * 256;
    int row = c >> 3, sl = c & 7;
    int kc = sl ^ (row & 7);
    async16(Ab + (long)row * K + kc * 8, &sA[0][c * 8]);
    async16(Bb + (long)row * K + kc * 8, &sB[0][c * 8]);
  }

  int nk = K >> 6;
  for (int kt = 0; kt < nk; ++kt) {
    int cur = kt & 1;
    __syncthreads();  // drains kt's loads + barrier; full fence
    if (kt + 1 < nk) {
      int k0n = (kt + 1) << 6;
#pragma unroll
      for (int it = 0; it < 4; ++it) {
        int c = tid + it * 256;
        int row = c >> 3, sl = c & 7;
        int kc = k0n + ((sl ^ (row & 7)) << 3);
        async16(Ab + (long)row * K + kc, &sA[cur ^ 1][c * 8]);
        async16(Bb + (long)row * K + kc, &sB[cur ^ 1][c * 8]);
      }
    }
#pragma unroll
    for (int ks = 0; ks < 2; ++ks) {
      bf16x8 af[4], bfr[4];
#pragma unroll
      for (int i = 0; i < 4; ++i) {
        int rowa = wr * 64 + i * 16 + l15;
        int slot = (ks * 4 + quad) ^ (rowa & 7);
        af[i] = *(const bf16x8*)(&sA[cur][rowa * 64 + slot * 8]);
      }
#pragma unroll
      for (int j = 0; j < 4; ++j) {
        int rowb = wc * 64 + j * 16 + l15;
        int slot = (ks * 4 + quad) ^ (rowb & 7);
        bfr[j] = *(const bf16x8*)(&sB[cur][rowb * 64 + slot * 8]);
      }
#pragma unroll
      for (int i = 0; i < 4; ++i)
#pragma unroll
        for (int j = 0; j < 4; ++j)
          acc[i][j] = mfma16(af[i], bfr[j], acc[i][j]);
    }
  }
#pragma unroll
  for (int i = 0; i < 4; ++i) {
#pragma unroll
    for (int j = 0; j < 4; ++j) {
      int col = (int)tn + wc * 64 + j * 16 + l15;
      if (col < Nc) {
        bool ropeT = false;
        int fi = 0;
        if constexpr (ROPE) {
          int d = col % 192;
          ropeT = (d >= 128);
          fi = (d - 128) & ~1;
        }
#pragma unroll
        for (int r = 0; r < 4; ++r) {
          long row = tm + wr * 64 + i * 16 + quad * 4 + r;
          float v = acc[i][j][r];
          if constexpr (ROPE) {
            float partner = __shfl_xor(v, 1);
            if (ropeT) {
              int si = (int)row & (S_ - 1);
              float cv = cs[si * 64 + fi], sv = sn[si * 64 + fi];
              v = (l15 & 1) ? (partner * sv + v * cv)
                            : (v * cv - partner * sv);
            }
            v *= QSCALE2;  // fold softmax scale*log2e into Q
          }
          if constexpr (sizeof(OUT_T) == 2) C[row * ldc + col] = f2bf(v);
          else                              C[row * ldc + col] = v;
        }
      }
    }
  }
}

// ---------------- kv_b GEMM with fused swizzle epilogue + krfill --------------
// (unchanged from R10: BK=32, 4-slot swizzle, fused krfill in nope epilogue)
__global__ __launch_bounds__(256)
void gemm_kvb_k(const u16* __restrict__ A, const u16* __restrict__ Bt,
                u16* __restrict__ kswz, u16* __restrict__ vswz,
                const u16* __restrict__ kr) {
  const int K = 512;
  __shared__ __align__(16) u16 sA[2][128 * 32];
  __shared__ __align__(16) u16 sB[2][128 * 32];
  int tid = threadIdx.x;
  int lane = tid & 63, w = tid >> 6;
  int wr = w >> 1, wc = w & 1;
  int l15 = lane & 15, quad = lane >> 4;
  int gx = gridDim.x;
  int nl = xcd_chunk(blockIdx.x + gx * blockIdx.y, gx * gridDim.y);
  long tm = (long)(nl / gx) * 128;
  long tn = (long)(nl % gx) * 128;
  const u16* Ab = A + tm * K;
  const u16* Bb = Bt + tn * K;
  f32x4 acc[4][4] = {};

#pragma unroll
  for (int it = 0; it < 2; ++it) {
    int c = tid + it * 256;
    int row = c >> 2, sl = c & 3;
    int kc = sl ^ ((row >> 1) & 3);
    async16(Ab + (long)row * K + kc * 8, &sA[0][c * 8]);
    async16(Bb + (long)row * K + kc * 8, &sB[0][c * 8]);
  }

  const int nk = K >> 5;  // 16
  for (int kt = 0; kt < nk; ++kt) {
    int cur = kt & 1;
    __syncthreads();
    if (kt + 1 < nk) {
      int k0n = (kt + 1) << 5;
#pragma unroll
      for (int it = 0; it < 2; ++it) {
        int c = tid + it * 256;
        int row = c >> 2, sl = c & 3;
        int kc = sl ^ ((row >> 1) & 3);
        async16(Ab + (long)row * K + k0n + kc * 8, &sA[cur ^ 1][c * 8]);
        async16(Bb + (long)row * K + k0n + kc * 8, &sB[cur ^ 1][c * 8]);
      }
    }
    bf16x8 af[4], bfr[4];
#pragma unroll
    for (int i = 0; i < 4; ++i) {
      int rowa = wr * 64 + i * 16 + l15;
      int slot = quad ^ ((rowa >> 1) & 3);
      af[i] = *(const bf16x8*)(&sA[cur][(rowa * 4 + slot) * 8]);
    }
#pragma unroll
    for (int j = 0; j < 4; ++j) {
      int rowb = wc * 64 + j * 16 + l15;
      int slot = quad ^ ((rowb >> 1) & 3);
      bfr[j] = *(const bf16x8*)(&sB[cur][(rowb * 4 + slot) * 8]);
    }
#pragma unroll
    for (int i = 0; i < 4; ++i)
#pragma unroll
      for (int j = 0; j < 4; ++j)
        acc[i][j] = mfma16(af[i], bfr[j], acc[i][j]);
  }

  int h = (int)(tn >> 8);
  int b = (int)(tm >> 11);
  int kt0 = ((int)tm & 2047) >> 6;
  int tile = (b * 16 + h) * 32 + kt0 + wr;
  if ((tn & 255) == 0) {
    u16* dst = kswz + (long)tile * 12288;
#pragma unroll
    for (int i = 0; i < 4; ++i) {
#pragma unroll
      for (int j = 0; j < 4; ++j) {
        int frag = quad * 6 + wc * 2 + (j >> 1);
        int chunk = frag * 64 + ((j & 1) * 2 + (l15 >> 3)) * 16 + i * 4;
#pragma unroll
        for (int r = 0; r < 4; ++r)
          dst[(chunk + r) * 8 + (l15 & 7)] = f2bf(acc[i][j][r]);
      }
    }
    // fused krfill: rope frags (kg*6+4,5) of this block's 2 tiles from kr
#pragma unroll
    for (int it = 0; it < 4; ++it) {
      int c = tid + it * 256;           // 0..1023
      int tt = c >> 9;                  // tile within block (0..1)
      int cc = c & 511;
      int lane2 = cc & 63, fd = cc >> 6;
      int kg = fd >> 1, dbr = fd & 1;
      int sl = lane2 & 15;
      int key = (kt0 + tt) * 64 + (sl >> 2) * 16 + kg * 4 + (sl & 3);
      int doff = dbr * 32 + (lane2 >> 4) * 8;
      int frag = kg * 6 + 4 + dbr;
      u16* dst2 = kswz + (long)((b * 16 + h) * 32 + kt0 + tt) * 12288;
      *(f32x4*)(dst2 + (frag * 64 + lane2) * 8) =
          *(const f32x4*)(kr + ((long)(b * S_ + key)) * 64 + doff);
    }
  } else {
    u16* dst = vswz + (long)tile * 8192;
    int kq = quad >> 1;
    int e0 = (quad & 1) * 4;
#pragma unroll
    for (int i = 0; i < 4; ++i) {
#pragma unroll
      for (int j = 0; j < 4; ++j) {
        int frag = kq * 8 + wc * 4 + j;
        u16x4 pk;
#pragma unroll
        for (int r = 0; r < 4; ++r) pk[r] = f2bf(acc[i][j][r]);
        *(u16x4*)(dst + (frag * 64 + i * 16 + l15) * 8 + e0) = pk;
      }
    }
  }
}

// ---------------- merged RMSNorm (q rows, kv rows) + krope --------------------
__global__ __launch_bounds__(256)
void rmsnorm2_k(const float* __restrict__ qsrc, int ldq,
                const float* __restrict__ kvsrc, int ldkv,
                const float* __restrict__ wq, const float* __restrict__ wkv,
                u16* __restrict__ qout, u16* __restrict__ kvout,
                const float* __restrict__ cs, const float* __restrict__ sn,
                u16* __restrict__ krout) {
  int blk = blockIdx.x;
  if (blk >= 8192) {
    int idx = (blk - 8192) * 256 + threadIdx.x;
    int row = idx >> 5, i = idx & 31;
    int s = row & (S_ - 1);
    const float* src = qsrc + 2048;
    float xr = src[(long)row * ldq + 2 * i];
    float xi = src[(long)row * ldq + 2 * i + 1];
    float cv = cs[s * 64 + 2 * i], sv = sn[s * 64 + 2 * i];
    krout[(long)row * 64 + 2 * i]     = f2bf(xr * cv - xi * sv);
    krout[(long)row * 64 + 2 * i + 1] = f2bf(xr * sv + xi * cv);
    return;
  }
  const float* x; const float* wt; u16* o; int N;
  if (blk < 4096) { x = qsrc + (long)blk * ldq;  wt = wq;  o = qout + (long)blk * 1536;  N = 1536; }
  else { blk -= 4096; x = kvsrc + (long)blk * ldkv; wt = wkv; o = kvout + (long)blk * 512; N = 512; }
  float ss = 0.f;
  for (int i = threadIdx.x; i < N; i += 256) { float v = x[i]; ss += v * v; }
#pragma unroll
  for (int off = 32; off; off >>= 1) ss += __shfl_down(ss, off);
  __shared__ float red[4];
  if ((threadIdx.x & 63) == 0) red[threadIdx.x >> 6] = ss;
  __syncthreads();
  float inv = rsqrtf((red[0] + red[1] + red[2] + red[3]) / N + 1e-6f);
  for (int i = threadIdx.x; i < N; i += 256) o[i] = f2bf(wt[i] * x[i] * inv);
}

// ---------------- flash attention ---------------------------------------------
// LDS-BW-bound fix: V fragments are read DIRECTLY from global (L2-resident,
// XCD-pinned by the block swizzle) instead of LDS -- splits the 160KB/blk/kt
// operand traffic between the LDS pipe (K, 96KB) and the L2/TA pipe (V, 64KB)
// which run concurrently. V loads issue before/under QK^T to hide L2 latency.
// sV eliminated: LDS 80KB -> 48KB. K stays LDS double-buffered (issue-early).
__global__ __launch_bounds__(256, 2)
void attn_k(const u16* __restrict__ qb, const u16* __restrict__ kswz,
            const u16* __restrict__ vswz, u16* __restrict__ attnO) {
  int lin = blockIdx.x + 16 * blockIdx.y;  // 0..511
  int xcd = lin & 7;
  int j = lin >> 3;                        // 0..63
  int bh = (xcd << 2) + (j >> 4);          // 4 bh per XCD
  int qt = j & 15;
  int b = bh >> 4, h = bh & 15;
  int tid = threadIdx.x, lane = tid & 63, w = tid >> 6;
  int l15 = lane & 15, quad = lane >> 4;
  int qrow0 = qt * 128 + w * 32;

  __shared__ __align__(16) u16 sK[2][24 * 64 * 8];

  const u16* Kb = kswz + (long)bh * 32 * 12288;
  const u16* Vb = vswz + (long)bh * 32 * 8192;

  bf16x8 qf[2][6];
#pragma unroll
  for (int rg = 0; rg < 2; ++rg) {
    const u16* qp = qb + ((long)(b * S_ + qrow0 + rg * 16 + l15)) * 3072 + h * 192 + quad * 8;
#pragma unroll
    for (int kb = 0; kb < 6; ++kb) qf[rg][kb] = *(const bf16x8*)(qp + kb * 32);
  }

  union { u16 v[8]; bf16x8 b; } ones;
#pragma unroll
  for (int e = 0; e < 8; ++e) ones.v[e] = 0x3F80;  // bf16 1.0

  f32x4 o[2][8] = {};
  f32x4 lacc[2] = {};

#pragma unroll
  for (int i = 0; i < 6; ++i) { int c = tid + i * 256; async16(Kb + c * 8, &sK[0][c * 8]); }

#pragma unroll 1
  for (int kt = 0; kt < 32; ++kt) {
    int cur = kt & 1;
    __syncthreads();
    if (kt < 31) {
      const u16* Kt = Kb + (long)(kt + 1) * 12288;
#pragma unroll
      for (int i = 0; i < 6; ++i) { int c = tid + i * 256; async16(Kt + c * 8, &sK[cur ^ 1][c * 8]); }
    }

    const u16* kbase = sK[cur];
    const u16* Vt = Vb + (long)kt * 8192;

    // V first half (kq=0 frags): issue now, L2 latency hides under QK^T
    bf16x8 vf0[8], vf1[8];
#pragma unroll
    for (int f = 0; f < 8; ++f)
      vf0[f] = *(const bf16x8*)(Vt + (f * 64 + lane) * 8);

    // QK^T, swapped operands: D col = l15 = qrow, D row = key slot
    f32x4 s[2][4] = {};
    __builtin_amdgcn_s_setprio(1);
#pragma unroll
    for (int kg = 0; kg < 4; ++kg) {
#pragma unroll
      for (int db = 0; db < 6; ++db) {
        bf16x8 kf = *(const bf16x8*)(kbase + ((kg * 6 + db) * 64 + lane) * 8);
        s[0][kg] = mfma16(kf, qf[0][db], s[0][kg]);
        s[1][kg] = mfma16(kf, qf[1][db], s[1][kg]);
      }
    }
    __builtin_amdgcn_s_setprio(0);

    // V second half: issue before softmax; hides under softmax + PV kq=0
#pragma unroll
    for (int f = 0; f < 8; ++f)
      vf1[f] = *(const bf16x8*)(Vt + ((8 + f) * 64 + lane) * 8);

    // softmax numerator (scale pre-folded into Q) + pack to PV A-operand
    bf16x8 pf[2][2];
#pragma unroll
    for (int rg = 0; rg < 2; ++rg) {
#pragma unroll
      for (int kg = 0; kg < 4; ++kg) {
#pragma unroll
        for (int r = 0; r < 4; ++r)
          s[rg][kg][r] = __builtin_amdgcn_exp2f(s[rg][kg][r]);
      }
#pragma unroll
      for (int kq = 0; kq < 2; ++kq) {
        union { unsigned wd[4]; bf16x8 v; } u;
        asm("v_cvt_pk_bf16_f32 %0, %1, %2"
            : "=v"(u.wd[0]) : "v"(s[rg][2 * kq][0]), "v"(s[rg][2 * kq][1]));
        asm("v_cvt_pk_bf16_f32 %0, %1, %2"
            : "=v"(u.wd[1]) : "v"(s[rg][2 * kq][2]), "v"(s[rg][2 * kq][3]));
        asm("v_cvt_pk_bf16_f32 %0, %1, %2"
            : "=v"(u.wd[2]) : "v"(s[rg][2 * kq + 1][0]), "v"(s[rg][2 * kq + 1][1]));
        asm("v_cvt_pk_bf16_f32 %0, %1, %2"
            : "=v"(u.wd[3]) : "v"(s[rg][2 * kq + 1][2]), "v"(s[rg][2 * kq + 1][3]));
        pf[rg][kq] = u.v;
      }
      // row-sums in the MFMA pipe: D[q,*] += sum_k P[q,k]
      lacc[rg] = mfma16(pf[rg][0], ones.b, lacc[rg]);
      lacc[rg] = mfma16(pf[rg][1], ones.b, lacc[rg]);
    }

    // PV (V from registers, loaded off the L2 pipe)
    __builtin_amdgcn_s_setprio(1);
#pragma unroll
    for (int j2 = 0; j2 < 8; ++j2) {
      o[0][j2] = mfma16(pf[0][0], vf0[j2], o[0][j2]);
      o[1][j2] = mfma16(pf[1][0], vf0[j2], o[1][j2]);
    }
#pragma unroll
    for (int j2 = 0; j2 < 8; ++j2) {
      o[0][j2] = mfma16(pf[0][1], vf1[j2], o[0][j2]);
      o[1][j2] = mfma16(pf[1][1], vf1[j2], o[1][j2]);
    }
    __builtin_amdgcn_s_setprio(0);
  }

  // lacc[rg][r] = rowsum for q-row quad*4+r (any column) -> direct reciprocal.
#pragma unroll
  for (int rg = 0; rg < 2; ++rg) {
    u16* op = attnO + ((long)(b * S_ + qrow0 + rg * 16)) * 2048 + h * 128;
    float invr[4];
#pragma unroll
    for (int r = 0; r < 4; ++r) invr[r] = 1.f / lacc[rg][r];
#pragma unroll
    for (int j2 = 0; j2 < 8; ++j2)
#pragma unroll
      for (int r = 0; r < 4; ++r)
        op[(long)(quad * 4 + r) * 2048 + j2 * 16 + l15] = f2bf(o[rg][j2][r] * invr[r]);
  }
}

extern "C" void kernel_launch(void* const* d_in, const int* in_sizes, int n_in,
                              void* d_out, int out_size, void* d_ws, size_t ws_size,
                              hipStream_t stream) {
  const float* hs      = (const float*)d_in[0];
  const float* cosb    = (const float*)d_in[1];
  const float* sinb    = (const float*)d_in[2];
  const float* q_a_w   = (const float*)d_in[3];
  const float* q_a_ln  = (const float*)d_in[4];
  const float* q_b_w   = (const float*)d_in[5];
  const float* kv_a_w  = (const float*)d_in[6];
  const float* kv_a_ln = (const float*)d_in[7];
  const float* kv_b_w  = (const float*)d_in[8];
  const float* o_w     = (const float*)d_in[9];
  float* out = (float*)d_out;
  (void)in_sizes; (void)n_in; (void)out_size; (void)ws_size;

  char* p = (char*)d_ws;
  auto alloc = [&](size_t b) { char* r = p; p += (b + 255) & ~((size_t)255); return r; };
  u16*   hs_bf  = (u16*)  alloc((size_t)4096 * 2048 * 2);   // 16.8 MB
  u16*   qakvT  = (u16*)  alloc((size_t)2176 * 2048 * 2);   // q_a^T(1536) ++ kv_a^T(640 pad)
  u16*   qbwT   = (u16*)  alloc((size_t)3072 * 1536 * 2);
  u16*   kvbwT  = (u16*)  alloc((size_t)4096 * 512  * 2);
  u16*   owT    = (u16*)  alloc((size_t)2048 * 2048 * 2);
  float* qa_ckv = (float*)alloc((size_t)4096 * 2176 * 4);   // 35.7 MB
  u16*   qan    = (u16*)  alloc((size_t)4096 * 1536 * 2);
  u16*   ckvn   = (u16*)  alloc((size_t)4096 * 512  * 2);
  u16*   kr     = (u16*)  alloc((size_t)4096 * 64   * 2);
  u16*   qbuf   = (u16*)  alloc((size_t)4096 * 3072 * 2);
  u16*   aO     = (u16*)  alloc((size_t)4096 * 2048 * 2);
  // aliases onto dead buffers:
  // kswz: 1024*12288*2 = 25.2 MB <= qa_ckv (35.7 MB, dead after rmsnorm/krope)
  // vswz: 1024*8192*2  = 16.8 MB <= hs_bf (16.8 MB, dead after a-proj GEMM)
  u16* kswz = (u16*)qa_ckv;
  u16* vswz = (u16*)hs_bf;

  // fused prep: hs cast + all 5 weight transposes (one launch)
  prep_k<<<19200, 256, 0, stream>>>(hs, hs_bf, q_a_w, kv_a_w, q_b_w, kv_b_w,
                                    o_w, qakvT, qbwT, kvbwT, owT);

  // fused q_a + kv_a projection: C = hs_bf @ [q_a | kv_a]^T  (4096 x 2176 f32)
  gemm_bt_k<float, false><<<dim3(17, 32), 256, 0, stream>>>(
      hs_bf, qakvT, qa_ckv, 2048, 2176, 2176, nullptr, nullptr);
  // rmsnorm (q + kv) + krope in one launch
  rmsnorm2_k<<<8704, 256, 0, stream>>>(qa_ckv, 2176, qa_ckv + 1536, 2176,
                                       q_a_ln, kv_a_ln, qan, ckvn,
                                       cosb, sinb, kr);
  // q_b with fused interleaved-RoPE epilogue (+ folded softmax scale)
  gemm_bt_k<u16, true><<<dim3(24, 32), 256, 0, stream>>>(
      qan, qbwT, qbuf, 1536, 3072, 3072, cosb, sinb);
  // kv_b with fused swizzle epilogue + krfill (writes all of kswz + vswz)
  gemm_kvb_k<<<dim3(32, 32), 256, 0, stream>>>(ckvn, kvbwT, kswz, vswz, kr);
  attn_k<<<dim3(16, 32), 256, 0, stream>>>(qbuf, kswz, vswz, aO);
  gemm_bt_k<float, false><<<dim3(16, 32), 256, 0, stream>>>(
      aO, owT, out, 2048, 2048, 2048, nullptr, nullptr);
}

// Round 12
// 461.989 us; speedup vs baseline: 1.0298x; 1.0298x over previous
//
#include <hip/hip_runtime.h>

typedef unsigned short u16;
typedef __bf16 bf16x8 __attribute__((ext_vector_type(8)));
typedef float f32x4 __attribute__((ext_vector_type(4)));
typedef u16 u16x4 __attribute__((ext_vector_type(4)));

#define S_ 2048

__device__ __forceinline__ u16 f2bf(float f) {
  union { float f; unsigned u; } v; v.f = f;
  unsigned r = v.u + 0x7fffu + ((v.u >> 16) & 1u);
  return (u16)(r >> 16);
}

__device__ __forceinline__ f32x4 mfma16(bf16x8 a, bf16x8 b, f32x4 c) {
  return __builtin_amdgcn_mfma_f32_16x16x32_bf16(a, b, c, 0, 0, 0);
}

__device__ __forceinline__ void async16(const void* g, void* l) {
  __builtin_amdgcn_global_load_lds((__attribute__((address_space(1))) void*)g,
                                   (__attribute__((address_space(3))) void*)l,
                                   16, 0, 0);
}

// 1/sqrt(192) * log2(e): folded into q_b output so attn softmax is 2^s
// (single v_exp_f32 via __builtin_amdgcn_exp2f; libm exp2f was R7's regression)
#define QSCALE2 0.10411756755f

// ---------------- fused prep: hs cast (blk<4096) + 5 weight transposes --------
__global__ __launch_bounds__(256)
void prep_k(const float* __restrict__ hs, u16* __restrict__ hs_bf,
            const float* __restrict__ q_a_w, const float* __restrict__ kv_a_w,
            const float* __restrict__ q_b_w, const float* __restrict__ kv_b_w,
            const float* __restrict__ o_w,
            u16* __restrict__ qakvT, u16* __restrict__ qbwT,
            u16* __restrict__ kvbwT, u16* __restrict__ owT) {
  int blk = blockIdx.x;
  int tid = threadIdx.x;
  if (blk < 4096) {
    int i = blk * 256 + tid;
    f32x4 a = ((const f32x4*)hs)[2 * i], b = ((const f32x4*)hs)[2 * i + 1];
    union { u16 v[8]; f32x4 q; } u;
#pragma unroll
    for (int e = 0; e < 4; ++e) { u.v[e] = f2bf(a[e]); u.v[4 + e] = f2bf(b[e]); }
    ((f32x4*)hs_bf)[i] = u.q;
    return;
  }
  blk -= 4096;
  const float* W; u16* Wt; int K, N, gx;
  if (blk < 3072)       { W = q_a_w;  Wt = qakvT;                     K = 2048; N = 1536; gx = 64; }
  else if (blk < 4352)  { blk -= 3072;  W = kv_a_w; Wt = qakvT + (long)1536 * 2048; K = 2048; N = 576;  gx = 64; }
  else if (blk < 8960)  { blk -= 4352;  W = q_b_w;  Wt = qbwT;  K = 1536; N = 3072; gx = 48; }
  else if (blk < 11008) { blk -= 8960;  W = kv_b_w; Wt = kvbwT; K = 512;  N = 4096; gx = 16; }
  else                  { blk -= 11008; W = o_w;    Wt = owT;   K = 2048; N = 2048; gx = 64; }
  int k0 = (blk % gx) * 32, n0 = (blk / gx) * 32;
  int tx = tid & 31, ty = tid >> 5;
  __shared__ float tile[32][33];
#pragma unroll
  for (int r = 0; r < 32; r += 8) {
    int n = n0 + tx;
    tile[ty + r][tx] = (n < N) ? W[(long)(k0 + ty + r) * N + n] : 0.f;
  }
  __syncthreads();
#pragma unroll
  for (int r = 0; r < 32; r += 8) {
    Wt[(long)(n0 + ty + r) * K + k0 + tx] = f2bf(tile[tx][ty + r]);
  }
}

// XCD-chunked bijective block remap (T1): wgid%8 selects the XCD.
__device__ __forceinline__ int xcd_chunk(int lin, int nwg) {
  if ((nwg & 7) == 0) return (lin & 7) * (nwg >> 3) + (lin >> 3);
  return lin;
}

// ---------------- C[M,N] = A[M,K] @ Bt[N,K]^T, optional fused RoPE epilogue ---
// 128x128 tile, BK=32 (R10-proven; BK=64 regressed in R11).
// Double-buffered issue-early/drain-at-sync pipeline; 4-slot XOR swizzle.
template <typename OUT_T, bool ROPE>
__global__ __launch_bounds__(256)
void gemm_bt_k(const u16* __restrict__ A, const u16* __restrict__ Bt,
               OUT_T* __restrict__ C, int K, int Nc, int ldc,
               const float* __restrict__ cs, const float* __restrict__ sn) {
  __shared__ __align__(16) u16 sA[2][128 * 32];
  __shared__ __align__(16) u16 sB[2][128 * 32];
  int tid = threadIdx.x;
  int lane = tid & 63, w = tid >> 6;
  int wr = w >> 1, wc = w & 1;
  int l15 = lane & 15, quad = lane >> 4;
  int gx = gridDim.x;
  int nl = xcd_chunk(blockIdx.x + gx * blockIdx.y, gx * gridDim.y);
  long tm = (long)(nl / gx) * 128;
  long tn = (long)(nl % gx) * 128;
  const u16* Ab = A + tm * K;
  const u16* Bb = Bt + tn * K;
  f32x4 acc[4][4] = {};

#pragma unroll
  for (int it = 0; it < 2; ++it) {
    int c = tid + it * 256;
    int row = c >> 2, sl = c & 3;
    int kc = sl ^ ((row >> 1) & 3);
    async16(Ab + (long)row * K + kc * 8, &sA[0][c * 8]);
    async16(Bb + (long)row * K + kc * 8, &sB[0][c * 8]);
  }

  int nk = K >> 5;
  for (int kt = 0; kt < nk; ++kt) {
    int cur = kt & 1;
    __syncthreads();  // drains kt's loads + barrier; full fence
    if (kt + 1 < nk) {
      int k0n = (kt + 1) << 5;
#pragma unroll
      for (int it = 0; it < 2; ++it) {
        int c = tid + it * 256;
        int row = c >> 2, sl = c & 3;
        int kc = sl ^ ((row >> 1) & 3);
        async16(Ab + (long)row * K + k0n + kc * 8, &sA[cur ^ 1][c * 8]);
        async16(Bb + (long)row * K + k0n + kc * 8, &sB[cur ^ 1][c * 8]);
      }
    }
    bf16x8 af[4], bfr[4];
#pragma unroll
    for (int i = 0; i < 4; ++i) {
      int rowa = wr * 64 + i * 16 + l15;
      int slot = quad ^ ((rowa >> 1) & 3);
      af[i] = *(const bf16x8*)(&sA[cur][(rowa * 4 + slot) * 8]);
    }
#pragma unroll
    for (int j = 0; j < 4; ++j) {
      int rowb = wc * 64 + j * 16 + l15;
      int slot = quad ^ ((rowb >> 1) & 3);
      bfr[j] = *(const bf16x8*)(&sB[cur][(rowb * 4 + slot) * 8]);
    }
#pragma unroll
    for (int i = 0; i < 4; ++i)
#pragma unroll
      for (int j = 0; j < 4; ++j)
        acc[i][j] = mfma16(af[i], bfr[j], acc[i][j]);
  }
#pragma unroll
  for (int i = 0; i < 4; ++i) {
#pragma unroll
    for (int j = 0; j < 4; ++j) {
      int col = (int)tn + wc * 64 + j * 16 + l15;
      if (col < Nc) {
        bool ropeT = false;
        int fi = 0;
        if constexpr (ROPE) {
          int d = col % 192;
          ropeT = (d >= 128);
          fi = (d - 128) & ~1;
        }
#pragma unroll
        for (int r = 0; r < 4; ++r) {
          long row = tm + wr * 64 + i * 16 + quad * 4 + r;
          float v = acc[i][j][r];
          if constexpr (ROPE) {
            float partner = __shfl_xor(v, 1);
            if (ropeT) {
              int si = (int)row & (S_ - 1);
              float cv = cs[si * 64 + fi], sv = sn[si * 64 + fi];
              v = (l15 & 1) ? (partner * sv + v * cv)
                            : (v * cv - partner * sv);
            }
            v *= QSCALE2;  // fold softmax scale*log2e into Q
          }
          if constexpr (sizeof(OUT_T) == 2) C[row * ldc + col] = f2bf(v);
          else                              C[row * ldc + col] = v;
        }
      }
    }
  }
}

// ---------------- kv_b GEMM with fused swizzle epilogue + krfill --------------
__global__ __launch_bounds__(256)
void gemm_kvb_k(const u16* __restrict__ A, const u16* __restrict__ Bt,
                u16* __restrict__ kswz, u16* __restrict__ vswz,
                const u16* __restrict__ kr) {
  const int K = 512;
  __shared__ __align__(16) u16 sA[2][128 * 32];
  __shared__ __align__(16) u16 sB[2][128 * 32];
  int tid = threadIdx.x;
  int lane = tid & 63, w = tid >> 6;
  int wr = w >> 1, wc = w & 1;
  int l15 = lane & 15, quad = lane >> 4;
  int gx = gridDim.x;
  int nl = xcd_chunk(blockIdx.x + gx * blockIdx.y, gx * gridDim.y);
  long tm = (long)(nl / gx) * 128;
  long tn = (long)(nl % gx) * 128;
  const u16* Ab = A + tm * K;
  const u16* Bb = Bt + tn * K;
  f32x4 acc[4][4] = {};

#pragma unroll
  for (int it = 0; it < 2; ++it) {
    int c = tid + it * 256;
    int row = c >> 2, sl = c & 3;
    int kc = sl ^ ((row >> 1) & 3);
    async16(Ab + (long)row * K + kc * 8, &sA[0][c * 8]);
    async16(Bb + (long)row * K + kc * 8, &sB[0][c * 8]);
  }

  const int nk = K >> 5;  // 16
  for (int kt = 0; kt < nk; ++kt) {
    int cur = kt & 1;
    __syncthreads();
    if (kt + 1 < nk) {
      int k0n = (kt + 1) << 5;
#pragma unroll
      for (int it = 0; it < 2; ++it) {
        int c = tid + it * 256;
        int row = c >> 2, sl = c & 3;
        int kc = sl ^ ((row >> 1) & 3);
        async16(Ab + (long)row * K + k0n + kc * 8, &sA[cur ^ 1][c * 8]);
        async16(Bb + (long)row * K + k0n + kc * 8, &sB[cur ^ 1][c * 8]);
      }
    }
    bf16x8 af[4], bfr[4];
#pragma unroll
    for (int i = 0; i < 4; ++i) {
      int rowa = wr * 64 + i * 16 + l15;
      int slot = quad ^ ((rowa >> 1) & 3);
      af[i] = *(const bf16x8*)(&sA[cur][(rowa * 4 + slot) * 8]);
    }
#pragma unroll
    for (int j = 0; j < 4; ++j) {
      int rowb = wc * 64 + j * 16 + l15;
      int slot = quad ^ ((rowb >> 1) & 3);
      bfr[j] = *(const bf16x8*)(&sB[cur][(rowb * 4 + slot) * 8]);
    }
#pragma unroll
    for (int i = 0; i < 4; ++i)
#pragma unroll
      for (int j = 0; j < 4; ++j)
        acc[i][j] = mfma16(af[i], bfr[j], acc[i][j]);
  }

  int h = (int)(tn >> 8);
  int b = (int)(tm >> 11);
  int kt0 = ((int)tm & 2047) >> 6;
  int tile = (b * 16 + h) * 32 + kt0 + wr;
  if ((tn & 255) == 0) {
    u16* dst = kswz + (long)tile * 12288;
#pragma unroll
    for (int i = 0; i < 4; ++i) {
#pragma unroll
      for (int j = 0; j < 4; ++j) {
        int frag = quad * 6 + wc * 2 + (j >> 1);
        int chunk = frag * 64 + ((j & 1) * 2 + (l15 >> 3)) * 16 + i * 4;
#pragma unroll
        for (int r = 0; r < 4; ++r)
          dst[(chunk + r) * 8 + (l15 & 7)] = f2bf(acc[i][j][r]);
      }
    }
    // fused krfill: rope frags (kg*6+4,5) of this block's 2 tiles from kr
#pragma unroll
    for (int it = 0; it < 4; ++it) {
      int c = tid + it * 256;           // 0..1023
      int tt = c >> 9;                  // tile within block (0..1)
      int cc = c & 511;
      int lane2 = cc & 63, fd = cc >> 6;
      int kg = fd >> 1, dbr = fd & 1;
      int sl = lane2 & 15;
      int key = (kt0 + tt) * 64 + (sl >> 2) * 16 + kg * 4 + (sl & 3);
      int doff = dbr * 32 + (lane2 >> 4) * 8;
      int frag = kg * 6 + 4 + dbr;
      u16* dst2 = kswz + (long)((b * 16 + h) * 32 + kt0 + tt) * 12288;
      *(f32x4*)(dst2 + (frag * 64 + lane2) * 8) =
          *(const f32x4*)(kr + ((long)(b * S_ + key)) * 64 + doff);
    }
  } else {
    u16* dst = vswz + (long)tile * 8192;
    int kq = quad >> 1;
    int e0 = (quad & 1) * 4;
#pragma unroll
    for (int i = 0; i < 4; ++i) {
#pragma unroll
      for (int j = 0; j < 4; ++j) {
        int frag = kq * 8 + wc * 4 + j;
        u16x4 pk;
#pragma unroll
        for (int r = 0; r < 4; ++r) pk[r] = f2bf(acc[i][j][r]);
        *(u16x4*)(dst + (frag * 64 + i * 16 + l15) * 8 + e0) = pk;
      }
    }
  }
}

// ---------------- merged RMSNorm (q rows, kv rows) + krope --------------------
__global__ __launch_bounds__(256)
void rmsnorm2_k(const float* __restrict__ qsrc, int ldq,
                const float* __restrict__ kvsrc, int ldkv,
                const float* __restrict__ wq, const float* __restrict__ wkv,
                u16* __restrict__ qout, u16* __restrict__ kvout,
                const float* __restrict__ cs, const float* __restrict__ sn,
                u16* __restrict__ krout) {
  int blk = blockIdx.x;
  if (blk >= 8192) {
    int idx = (blk - 8192) * 256 + threadIdx.x;
    int row = idx >> 5, i = idx & 31;
    int s = row & (S_ - 1);
    const float* src = qsrc + 2048;
    float xr = src[(long)row * ldq + 2 * i];
    float xi = src[(long)row * ldq + 2 * i + 1];
    float cv = cs[s * 64 + 2 * i], sv = sn[s * 64 + 2 * i];
    krout[(long)row * 64 + 2 * i]     = f2bf(xr * cv - xi * sv);
    krout[(long)row * 64 + 2 * i + 1] = f2bf(xr * sv + xi * cv);
    return;
  }
  const float* x; const float* wt; u16* o; int N;
  if (blk < 4096) { x = qsrc + (long)blk * ldq;  wt = wq;  o = qout + (long)blk * 1536;  N = 1536; }
  else { blk -= 4096; x = kvsrc + (long)blk * ldkv; wt = wkv; o = kvout + (long)blk * 512; N = 512; }
  float ss = 0.f;
  for (int i = threadIdx.x; i < N; i += 256) { float v = x[i]; ss += v * v; }
#pragma unroll
  for (int off = 32; off; off >>= 1) ss += __shfl_down(ss, off);
  __shared__ float red[4];
  if ((threadIdx.x & 63) == 0) red[threadIdx.x >> 6] = ss;
  __syncthreads();
  float inv = rsqrtf((red[0] + red[1] + red[2] + red[3]) / N + 1e-6f);
  for (int i = threadIdx.x; i < N; i += 256) o[i] = f2bf(wt[i] * x[i] * inv);
}

// ---------------- flash attention ---------------------------------------------
// ILP fix: QK^T loop nest swapped (db outer, kg inner) -- consecutive MFMAs
// hit 8 DIFFERENT accumulators (4 kg x 2 rg), dependency distance 8 instrs
// (~40cy > dependent-MFMA latency) instead of 2.  Accumulation order per
// accumulator unchanged (db still sequential) -> bit-identical.
// V read directly from global (L2-resident, XCD-pinned); K LDS-staged,
// double-buffered, issue-early/drain-at-sync.
__global__ __launch_bounds__(256, 2)
void attn_k(const u16* __restrict__ qb, const u16* __restrict__ kswz,
            const u16* __restrict__ vswz, u16* __restrict__ attnO) {
  int lin = blockIdx.x + 16 * blockIdx.y;  // 0..511
  int xcd = lin & 7;
  int j = lin >> 3;                        // 0..63
  int bh = (xcd << 2) + (j >> 4);          // 4 bh per XCD
  int qt = j & 15;
  int b = bh >> 4, h = bh & 15;
  int tid = threadIdx.x, lane = tid & 63, w = tid >> 6;
  int l15 = lane & 15, quad = lane >> 4;
  int qrow0 = qt * 128 + w * 32;

  __shared__ __align__(16) u16 sK[2][24 * 64 * 8];

  const u16* Kb = kswz + (long)bh * 32 * 12288;
  const u16* Vb = vswz + (long)bh * 32 * 8192;

  bf16x8 qf[2][6];
#pragma unroll
  for (int rg = 0; rg < 2; ++rg) {
    const u16* qp = qb + ((long)(b * S_ + qrow0 + rg * 16 + l15)) * 3072 + h * 192 + quad * 8;
#pragma unroll
    for (int kb = 0; kb < 6; ++kb) qf[rg][kb] = *(const bf16x8*)(qp + kb * 32);
  }

  union { u16 v[8]; bf16x8 b; } ones;
#pragma unroll
  for (int e = 0; e < 8; ++e) ones.v[e] = 0x3F80;  // bf16 1.0

  f32x4 o[2][8] = {};
  f32x4 lacc[2] = {};

#pragma unroll
  for (int i = 0; i < 6; ++i) { int c = tid + i * 256; async16(Kb + c * 8, &sK[0][c * 8]); }

#pragma unroll 1
  for (int kt = 0; kt < 32; ++kt) {
    int cur = kt & 1;
    __syncthreads();
    if (kt < 31) {
      const u16* Kt = Kb + (long)(kt + 1) * 12288;
#pragma unroll
      for (int i = 0; i < 6; ++i) { int c = tid + i * 256; async16(Kt + c * 8, &sK[cur ^ 1][c * 8]); }
    }

    const u16* kbase = sK[cur];
    const u16* Vt = Vb + (long)kt * 8192;

    // V first half: issue now, L2 latency hides under QK^T
    bf16x8 vf0[8], vf1[8];
#pragma unroll
    for (int f = 0; f < 8; ++f)
      vf0[f] = *(const bf16x8*)(Vt + (f * 64 + lane) * 8);

    // QK^T, swapped operands: D col = l15 = qrow, D row = key slot.
    // db OUTER: per-db batch of 4 kf reads, then 8 independent-chain MFMAs.
    f32x4 s[2][4] = {};
    __builtin_amdgcn_s_setprio(1);
#pragma unroll
    for (int db = 0; db < 6; ++db) {
      bf16x8 kf[4];
#pragma unroll
      for (int kg = 0; kg < 4; ++kg)
        kf[kg] = *(const bf16x8*)(kbase + ((kg * 6 + db) * 64 + lane) * 8);
#pragma unroll
      for (int kg = 0; kg < 4; ++kg) {
        s[0][kg] = mfma16(kf[kg], qf[0][db], s[0][kg]);
        s[1][kg] = mfma16(kf[kg], qf[1][db], s[1][kg]);
      }
    }
    __builtin_amdgcn_s_setprio(0);

    // V second half: issue before softmax; hides under softmax + PV kq=0
#pragma unroll
    for (int f = 0; f < 8; ++f)
      vf1[f] = *(const bf16x8*)(Vt + ((8 + f) * 64 + lane) * 8);

    // softmax numerator (scale pre-folded into Q) + pack to PV A-operand
    bf16x8 pf[2][2];
#pragma unroll
    for (int rg = 0; rg < 2; ++rg) {
#pragma unroll
      for (int kg = 0; kg < 4; ++kg) {
#pragma unroll
        for (int r = 0; r < 4; ++r)
          s[rg][kg][r] = __builtin_amdgcn_exp2f(s[rg][kg][r]);
      }
#pragma unroll
      for (int kq = 0; kq < 2; ++kq) {
        union { unsigned wd[4]; bf16x8 v; } u;
        asm("v_cvt_pk_bf16_f32 %0, %1, %2"
            : "=v"(u.wd[0]) : "v"(s[rg][2 * kq][0]), "v"(s[rg][2 * kq][1]));
        asm("v_cvt_pk_bf16_f32 %0, %1, %2"
            : "=v"(u.wd[1]) : "v"(s[rg][2 * kq][2]), "v"(s[rg][2 * kq][3]));
        asm("v_cvt_pk_bf16_f32 %0, %1, %2"
            : "=v"(u.wd[2]) : "v"(s[rg][2 * kq + 1][0]), "v"(s[rg][2 * kq + 1][1]));
        asm("v_cvt_pk_bf16_f32 %0, %1, %2"
            : "=v"(u.wd[3]) : "v"(s[rg][2 * kq + 1][2]), "v"(s[rg][2 * kq + 1][3]));
        pf[rg][kq] = u.v;
      }
      // row-sums in the MFMA pipe: D[q,*] += sum_k P[q,k]
      lacc[rg] = mfma16(pf[rg][0], ones.b, lacc[rg]);
      lacc[rg] = mfma16(pf[rg][1], ones.b, lacc[rg]);
    }

    // PV (V from registers, loaded off the L2 pipe)
    __builtin_amdgcn_s_setprio(1);
#pragma unroll
    for (int j2 = 0; j2 < 8; ++j2) {
      o[0][j2] = mfma16(pf[0][0], vf0[j2], o[0][j2]);
      o[1][j2] = mfma16(pf[1][0], vf0[j2], o[1][j2]);
    }
#pragma unroll
    for (int j2 = 0; j2 < 8; ++j2) {
      o[0][j2] = mfma16(pf[0][1], vf1[j2], o[0][j2]);
      o[1][j2] = mfma16(pf[1][1], vf1[j2], o[1][j2]);
    }
    __builtin_amdgcn_s_setprio(0);
  }

  // lacc[rg][r] = rowsum for q-row quad*4+r (any column) -> direct reciprocal.
#pragma unroll
  for (int rg = 0; rg < 2; ++rg) {
    u16* op = attnO + ((long)(b * S_ + qrow0 + rg * 16)) * 2048 + h * 128;
    float invr[4];
#pragma unroll
    for (int r = 0; r < 4; ++r) invr[r] = 1.f / lacc[rg][r];
#pragma unroll
    for (int j2 = 0; j2 < 8; ++j2)
#pragma unroll
      for (int r = 0; r < 4; ++r)
        op[(long)(quad * 4 + r) * 2048 + j2 * 16 + l15] = f2bf(o[rg][j2][r] * invr[r]);
  }
}

extern "C" void kernel_launch(void* const* d_in, const int* in_sizes, int n_in,
                              void* d_out, int out_size, void* d_ws, size_t ws_size,
                              hipStream_t stream) {
  const float* hs      = (const float*)d_in[0];
  const float* cosb    = (const float*)d_in[1];
  const float* sinb    = (const float*)d_in[2];
  const float* q_a_w   = (const float*)d_in[3];
  const float* q_a_ln  = (const float*)d_in[4];
  const float* q_b_w   = (const float*)d_in[5];
  const float* kv_a_w  = (const float*)d_in[6];
  const float* kv_a_ln = (const float*)d_in[7];
  const float* kv_b_w  = (const float*)d_in[8];
  const float* o_w     = (const float*)d_in[9];
  float* out = (float*)d_out;
  (void)in_sizes; (void)n_in; (void)out_size; (void)ws_size;

  char* p = (char*)d_ws;
  auto alloc = [&](size_t b) { char* r = p; p += (b + 255) & ~((size_t)255); return r; };
  u16*   hs_bf  = (u16*)  alloc((size_t)4096 * 2048 * 2);   // 16.8 MB
  u16*   qakvT  = (u16*)  alloc((size_t)2176 * 2048 * 2);   // q_a^T(1536) ++ kv_a^T(640 pad)
  u16*   qbwT   = (u16*)  alloc((size_t)3072 * 1536 * 2);
  u16*   kvbwT  = (u16*)  alloc((size_t)4096 * 512  * 2);
  u16*   owT    = (u16*)  alloc((size_t)2048 * 2048 * 2);
  float* qa_ckv = (float*)alloc((size_t)4096 * 2176 * 4);   // 35.7 MB
  u16*   qan    = (u16*)  alloc((size_t)4096 * 1536 * 2);
  u16*   ckvn   = (u16*)  alloc((size_t)4096 * 512  * 2);
  u16*   kr     = (u16*)  alloc((size_t)4096 * 64   * 2);
  u16*   qbuf   = (u16*)  alloc((size_t)4096 * 3072 * 2);
  u16*   aO     = (u16*)  alloc((size_t)4096 * 2048 * 2);
  // aliases onto dead buffers:
  // kswz: 1024*12288*2 = 25.2 MB <= qa_ckv (35.7 MB, dead after rmsnorm/krope)
  // vswz: 1024*8192*2  = 16.8 MB <= hs_bf (16.8 MB, dead after a-proj GEMM)
  u16* kswz = (u16*)qa_ckv;
  u16* vswz = (u16*)hs_bf;

  // fused prep: hs cast + all 5 weight transposes (one launch)
  prep_k<<<19200, 256, 0, stream>>>(hs, hs_bf, q_a_w, kv_a_w, q_b_w, kv_b_w,
                                    o_w, qakvT, qbwT, kvbwT, owT);

  // fused q_a + kv_a projection: C = hs_bf @ [q_a | kv_a]^T  (4096 x 2176 f32)
  gemm_bt_k<float, false><<<dim3(17, 32), 256, 0, stream>>>(
      hs_bf, qakvT, qa_ckv, 2048, 2176, 2176, nullptr, nullptr);
  // rmsnorm (q + kv) + krope in one launch
  rmsnorm2_k<<<8704, 256, 0, stream>>>(qa_ckv, 2176, qa_ckv + 1536, 2176,
                                       q_a_ln, kv_a_ln, qan, ckvn,
                                       cosb, sinb, kr);
  // q_b with fused interleaved-RoPE epilogue (+ folded softmax scale)
  gemm_bt_k<u16, true><<<dim3(24, 32), 256, 0, stream>>>(
      qan, qbwT, qbuf, 1536, 3072, 3072, cosb, sinb);
  // kv_b with fused swizzle epilogue + krfill (writes all of kswz + vswz)
  gemm_kvb_k<<<dim3(32, 32), 256, 0, stream>>>(ckvn, kvbwT, kswz, vswz, kr);
  attn_k<<<dim3(16, 32), 256, 0, stream>>>(qbuf, kswz, vswz, aO);
  gemm_bt_k<float, false><<<dim3(16, 32), 256, 0, stream>>>(
      aO, owT, out, 2048, 2048, 2048, nullptr, nullptr);
}

// Round 13
// 444.271 us; speedup vs baseline: 1.0709x; 1.0399x over previous
//
#include <hip/hip_runtime.h>

typedef unsigned short u16;
typedef __bf16 bf16x8 __attribute__((ext_vector_type(8)));
typedef float f32x4 __attribute__((ext_vector_type(4)));
typedef u16 u16x4 __attribute__((ext_vector_type(4)));

#define S_ 2048

__device__ __forceinline__ u16 f2bf(float f) {
  union { float f; unsigned u; } v; v.f = f;
  unsigned r = v.u + 0x7fffu + ((v.u >> 16) & 1u);
  return (u16)(r >> 16);
}

__device__ __forceinline__ f32x4 mfma16(bf16x8 a, bf16x8 b, f32x4 c) {
  return __builtin_amdgcn_mfma_f32_16x16x32_bf16(a, b, c, 0, 0, 0);
}

__device__ __forceinline__ void async16(const void* g, void* l) {
  __builtin_amdgcn_global_load_lds((__attribute__((address_space(1))) void*)g,
                                   (__attribute__((address_space(3))) void*)l,
                                   16, 0, 0);
}

// 1/sqrt(192) * log2(e): folded into q_b output so attn softmax is 2^s
#define QSCALE2 0.10411756755f

// XCD-chunked bijective block remap (T1): wgid%8 selects the XCD.
__device__ __forceinline__ int xcd_chunk(int lin, int nwg) {
  if ((nwg & 7) == 0) return (lin & 7) * (nwg >> 3) + (lin >> 3);
  return lin;
}

// ---------------- transpose body: W (K,N) f32 -> Wt (N,K) bf16 ----------------
__device__ __forceinline__ void transw_body(const float* __restrict__ W,
                                            u16* __restrict__ Wt, int K, int N,
                                            int blk, int gx, float* tile) {
  int tid = threadIdx.x;
  int k0 = (blk % gx) * 32, n0 = (blk / gx) * 32;
  int tx = tid & 31, ty = tid >> 5;
#pragma unroll
  for (int r = 0; r < 32; r += 8) {
    int n = n0 + tx;
    tile[(ty + r) * 33 + tx] = (n < N) ? W[(long)(k0 + ty + r) * N + n] : 0.f;
  }
  __syncthreads();
#pragma unroll
  for (int r = 0; r < 32; r += 8) {
    Wt[(long)(n0 + ty + r) * K + k0 + tx] = f2bf(tile[tx * 33 + ty + r]);
  }
}

// ---------------- GEMM body: C[M,N] = A[M,K] @ Bt[N,K]^T, opt. RoPE epilogue --
// 128x128 tile, BK=32, double-buffered issue-early/drain-at-sync, 4-slot XOR
// swizzle (R10-proven).  sAbuf/sBbuf: 2 x 4096 u16 each.
template <typename OUT_T, bool ROPE>
__device__ __forceinline__ void gemm_bt_body(
    const u16* __restrict__ A, const u16* __restrict__ Bt,
    OUT_T* __restrict__ C, int K, int Nc, int ldc,
    const float* __restrict__ cs, const float* __restrict__ sn,
    int nl, int gxT, u16* sAbuf, u16* sBbuf) {
  int tid = threadIdx.x;
  int lane = tid & 63, w = tid >> 6;
  int wr = w >> 1, wc = w & 1;
  int l15 = lane & 15, quad = lane >> 4;
  long tm = (long)(nl / gxT) * 128;
  long tn = (long)(nl % gxT) * 128;
  const u16* Ab = A + tm * K;
  const u16* Bb = Bt + tn * K;
  f32x4 acc[4][4] = {};

#pragma unroll
  for (int it = 0; it < 2; ++it) {
    int c = tid + it * 256;
    int row = c >> 2, sl = c & 3;
    int kc = sl ^ ((row >> 1) & 3);
    async16(Ab + (long)row * K + kc * 8, sAbuf + c * 8);
    async16(Bb + (long)row * K + kc * 8, sBbuf + c * 8);
  }

  int nk = K >> 5;
  for (int kt = 0; kt < nk; ++kt) {
    int cur = kt & 1;
    __syncthreads();  // drains kt's loads + barrier; full fence
    if (kt + 1 < nk) {
      int k0n = (kt + 1) << 5;
#pragma unroll
      for (int it = 0; it < 2; ++it) {
        int c = tid + it * 256;
        int row = c >> 2, sl = c & 3;
        int kc = sl ^ ((row >> 1) & 3);
        async16(Ab + (long)row * K + k0n + kc * 8, sAbuf + (cur ^ 1) * 4096 + c * 8);
        async16(Bb + (long)row * K + k0n + kc * 8, sBbuf + (cur ^ 1) * 4096 + c * 8);
      }
    }
    bf16x8 af[4], bfr[4];
#pragma unroll
    for (int i = 0; i < 4; ++i) {
      int rowa = wr * 64 + i * 16 + l15;
      int slot = quad ^ ((rowa >> 1) & 3);
      af[i] = *(const bf16x8*)(sAbuf + cur * 4096 + (rowa * 4 + slot) * 8);
    }
#pragma unroll
    for (int j = 0; j < 4; ++j) {
      int rowb = wc * 64 + j * 16 + l15;
      int slot = quad ^ ((rowb >> 1) & 3);
      bfr[j] = *(const bf16x8*)(sBbuf + cur * 4096 + (rowb * 4 + slot) * 8);
    }
#pragma unroll
    for (int i = 0; i < 4; ++i)
#pragma unroll
      for (int j = 0; j < 4; ++j)
        acc[i][j] = mfma16(af[i], bfr[j], acc[i][j]);
  }
#pragma unroll
  for (int i = 0; i < 4; ++i) {
#pragma unroll
    for (int j = 0; j < 4; ++j) {
      int col = (int)tn + wc * 64 + j * 16 + l15;
      if (col < Nc) {
        bool ropeT = false;
        int fi = 0;
        if constexpr (ROPE) {
          int d = col % 192;
          ropeT = (d >= 128);
          fi = (d - 128) & ~1;
        }
#pragma unroll
        for (int r = 0; r < 4; ++r) {
          long row = tm + wr * 64 + i * 16 + quad * 4 + r;
          float v = acc[i][j][r];
          if constexpr (ROPE) {
            float partner = __shfl_xor(v, 1);
            if (ropeT) {
              int si = (int)row & (S_ - 1);
              float cv = cs[si * 64 + fi], sv = sn[si * 64 + fi];
              v = (l15 & 1) ? (partner * sv + v * cv)
                            : (v * cv - partner * sv);
            }
            v *= QSCALE2;  // fold softmax scale*log2e into Q
          }
          if constexpr (sizeof(OUT_T) == 2) C[row * ldc + col] = f2bf(v);
          else                              C[row * ldc + col] = v;
        }
      }
    }
  }
}

// ---------------- kv_b GEMM body with fused swizzle epilogue + krfill ---------
__device__ __forceinline__ void gemm_kvb_body(
    const u16* __restrict__ A, const u16* __restrict__ Bt,
    u16* __restrict__ kswz, u16* __restrict__ vswz,
    const u16* __restrict__ kr, int nl, u16* sAbuf, u16* sBbuf) {
  const int K = 512;
  int tid = threadIdx.x;
  int lane = tid & 63, w = tid >> 6;
  int wr = w >> 1, wc = w & 1;
  int l15 = lane & 15, quad = lane >> 4;
  long tm = (long)(nl / 32) * 128;
  long tn = (long)(nl % 32) * 128;
  const u16* Ab = A + tm * K;
  const u16* Bb = Bt + tn * K;
  f32x4 acc[4][4] = {};

#pragma unroll
  for (int it = 0; it < 2; ++it) {
    int c = tid + it * 256;
    int row = c >> 2, sl = c & 3;
    int kc = sl ^ ((row >> 1) & 3);
    async16(Ab + (long)row * K + kc * 8, sAbuf + c * 8);
    async16(Bb + (long)row * K + kc * 8, sBbuf + c * 8);
  }

  const int nk = K >> 5;  // 16
  for (int kt = 0; kt < nk; ++kt) {
    int cur = kt & 1;
    __syncthreads();
    if (kt + 1 < nk) {
      int k0n = (kt + 1) << 5;
#pragma unroll
      for (int it = 0; it < 2; ++it) {
        int c = tid + it * 256;
        int row = c >> 2, sl = c & 3;
        int kc = sl ^ ((row >> 1) & 3);
        async16(Ab + (long)row * K + k0n + kc * 8, sAbuf + (cur ^ 1) * 4096 + c * 8);
        async16(Bb + (long)row * K + k0n + kc * 8, sBbuf + (cur ^ 1) * 4096 + c * 8);
      }
    }
    bf16x8 af[4], bfr[4];
#pragma unroll
    for (int i = 0; i < 4; ++i) {
      int rowa = wr * 64 + i * 16 + l15;
      int slot = quad ^ ((rowa >> 1) & 3);
      af[i] = *(const bf16x8*)(sAbuf + cur * 4096 + (rowa * 4 + slot) * 8);
    }
#pragma unroll
    for (int j = 0; j < 4; ++j) {
      int rowb = wc * 64 + j * 16 + l15;
      int slot = quad ^ ((rowb >> 1) & 3);
      bfr[j] = *(const bf16x8*)(sBbuf + cur * 4096 + (rowb * 4 + slot) * 8);
    }
#pragma unroll
    for (int i = 0; i < 4; ++i)
#pragma unroll
      for (int j = 0; j < 4; ++j)
        acc[i][j] = mfma16(af[i], bfr[j], acc[i][j]);
  }

  int h = (int)(tn >> 8);
  int b = (int)(tm >> 11);
  int kt0 = ((int)tm & 2047) >> 6;
  int tile = (b * 16 + h) * 32 + kt0 + wr;
  if ((tn & 255) == 0) {
    u16* dst = kswz + (long)tile * 12288;
#pragma unroll
    for (int i = 0; i < 4; ++i) {
#pragma unroll
      for (int j = 0; j < 4; ++j) {
        int frag = quad * 6 + wc * 2 + (j >> 1);
        int chunk = frag * 64 + ((j & 1) * 2 + (l15 >> 3)) * 16 + i * 4;
#pragma unroll
        for (int r = 0; r < 4; ++r)
          dst[(chunk + r) * 8 + (l15 & 7)] = f2bf(acc[i][j][r]);
      }
    }
    // fused krfill: rope frags (kg*6+4,5) of this block's 2 tiles from kr
#pragma unroll
    for (int it = 0; it < 4; ++it) {
      int c = tid + it * 256;           // 0..1023
      int tt = c >> 9;                  // tile within block (0..1)
      int cc = c & 511;
      int lane2 = cc & 63, fd = cc >> 6;
      int kg = fd >> 1, dbr = fd & 1;
      int sl = lane2 & 15;
      int key = (kt0 + tt) * 64 + (sl >> 2) * 16 + kg * 4 + (sl & 3);
      int doff = dbr * 32 + (lane2 >> 4) * 8;
      int frag = kg * 6 + 4 + dbr;
      u16* dst2 = kswz + (long)((b * 16 + h) * 32 + kt0 + tt) * 12288;
      *(f32x4*)(dst2 + (frag * 64 + lane2) * 8) =
          *(const f32x4*)(kr + ((long)(b * S_ + key)) * 64 + doff);
    }
  } else {
    u16* dst = vswz + (long)tile * 8192;
    int kq = quad >> 1;
    int e0 = (quad & 1) * 4;
#pragma unroll
    for (int i = 0; i < 4; ++i) {
#pragma unroll
      for (int j = 0; j < 4; ++j) {
        int frag = kq * 8 + wc * 4 + j;
        u16x4 pk;
#pragma unroll
        for (int r = 0; r < 4; ++r) pk[r] = f2bf(acc[i][j][r]);
        *(u16x4*)(dst + (frag * 64 + i * 16 + l15) * 8 + e0) = pk;
      }
    }
  }
}

// ---------------- prep: hs cast (blk<4096) + q_a/kv_a transposes --------------
__global__ __launch_bounds__(256)
void prep_k(const float* __restrict__ hs, u16* __restrict__ hs_bf,
            const float* __restrict__ q_a_w, const float* __restrict__ kv_a_w,
            u16* __restrict__ qakvT) {
  __shared__ float tile[32 * 33];
  int blk = blockIdx.x;
  int tid = threadIdx.x;
  if (blk < 4096) {
    int i = blk * 256 + tid;
    f32x4 a = ((const f32x4*)hs)[2 * i], b = ((const f32x4*)hs)[2 * i + 1];
    union { u16 v[8]; f32x4 q; } u;
#pragma unroll
    for (int e = 0; e < 4; ++e) { u.v[e] = f2bf(a[e]); u.v[4 + e] = f2bf(b[e]); }
    ((f32x4*)hs_bf)[i] = u.q;
    return;
  }
  blk -= 4096;
  if (blk < 3072) transw_body(q_a_w, qakvT, 2048, 1536, blk, 64, tile);
  else            transw_body(kv_a_w, qakvT + (long)1536 * 2048, 2048, 576,
                              blk - 3072, 64, tile);
}

// ---------------- a-proj GEMM (blocks <544) + late weight transposes ----------
// Transpose blocks (q_b_w/kv_b_w/o_w -> needed only by LATER dispatches) pack
// the a-proj tail: 544-block GEMM = 2.125/CU leaves CUs idle at ramp-down.
__global__ __launch_bounds__(256)
void aproj_trans_k(const u16* __restrict__ hs_bf, const u16* __restrict__ qakvT,
                   float* __restrict__ qa_ckv,
                   const float* __restrict__ q_b_w, const float* __restrict__ kv_b_w,
                   const float* __restrict__ o_w,
                   u16* __restrict__ qbwT, u16* __restrict__ kvbwT,
                   u16* __restrict__ owT) {
  __shared__ __align__(16) char smem[32768];
  int lin = blockIdx.x;
  if (lin < 544) {
    u16* sAbuf = (u16*)smem;
    u16* sBbuf = sAbuf + 8192;
    gemm_bt_body<float, false>(hs_bf, qakvT, qa_ckv, 2048, 2176, 2176,
                               nullptr, nullptr, xcd_chunk(lin, 544), 17,
                               sAbuf, sBbuf);
    return;
  }
  float* tile = (float*)smem;
  int blk = lin - 544;
  if (blk < 4608)      transw_body(q_b_w,  qbwT,  1536, 3072, blk, 48, tile);
  else if (blk < 6656) transw_body(kv_b_w, kvbwT, 512,  4096, blk - 4608, 16, tile);
  else                 transw_body(o_w,    owT,   2048, 2048, blk - 6656, 64, tile);
}

// ---------------- fused q_b GEMM (blocks <768) + kv_b GEMM (blocks >=768) -----
// Independent ops (both ready after rmsnorm); one dispatch overlaps their tails.
__global__ __launch_bounds__(256)
void qbkvb_k(const u16* __restrict__ qan, const u16* __restrict__ qbwT,
             u16* __restrict__ qbuf,
             const float* __restrict__ cs, const float* __restrict__ sn,
             const u16* __restrict__ ckvn, const u16* __restrict__ kvbwT,
             u16* __restrict__ kswz, u16* __restrict__ vswz,
             const u16* __restrict__ kr) {
  __shared__ __align__(16) char smem[32768];
  u16* sAbuf = (u16*)smem;
  u16* sBbuf = sAbuf + 8192;
  int lin = blockIdx.x;
  if (lin < 768) {
    gemm_bt_body<u16, true>(qan, qbwT, qbuf, 1536, 3072, 3072, cs, sn,
                            xcd_chunk(lin, 768), 24, sAbuf, sBbuf);
  } else {
    gemm_kvb_body(ckvn, kvbwT, kswz, vswz, kr,
                  xcd_chunk(lin - 768, 1024), sAbuf, sBbuf);
  }
}

// ---------------- standalone GEMM wrapper (o-proj) ----------------------------
template <typename OUT_T, bool ROPE>
__global__ __launch_bounds__(256)
void gemm_bt_k(const u16* __restrict__ A, const u16* __restrict__ Bt,
               OUT_T* __restrict__ C, int K, int Nc, int ldc,
               const float* __restrict__ cs, const float* __restrict__ sn) {
  __shared__ __align__(16) u16 sAbuf[2 * 4096];
  __shared__ __align__(16) u16 sBbuf[2 * 4096];
  int gx = gridDim.x;
  int nl = xcd_chunk(blockIdx.x + gx * blockIdx.y, gx * gridDim.y);
  gemm_bt_body<OUT_T, ROPE>(A, Bt, C, K, Nc, ldc, cs, sn, nl, gx, sAbuf, sBbuf);
}

// ---------------- merged RMSNorm (q rows, kv rows) + krope --------------------
__global__ __launch_bounds__(256)
void rmsnorm2_k(const float* __restrict__ qsrc, int ldq,
                const float* __restrict__ kvsrc, int ldkv,
                const float* __restrict__ wq, const float* __restrict__ wkv,
                u16* __restrict__ qout, u16* __restrict__ kvout,
                const float* __restrict__ cs, const float* __restrict__ sn,
                u16* __restrict__ krout) {
  int blk = blockIdx.x;
  if (blk >= 8192) {
    int idx = (blk - 8192) * 256 + threadIdx.x;
    int row = idx >> 5, i = idx & 31;
    int s = row & (S_ - 1);
    const float* src = qsrc + 2048;
    float xr = src[(long)row * ldq + 2 * i];
    float xi = src[(long)row * ldq + 2 * i + 1];
    float cv = cs[s * 64 + 2 * i], sv = sn[s * 64 + 2 * i];
    krout[(long)row * 64 + 2 * i]     = f2bf(xr * cv - xi * sv);
    krout[(long)row * 64 + 2 * i + 1] = f2bf(xr * sv + xi * cv);
    return;
  }
  const float* x; const float* wt; u16* o; int N;
  if (blk < 4096) { x = qsrc + (long)blk * ldq;  wt = wq;  o = qout + (long)blk * 1536;  N = 1536; }
  else { blk -= 4096; x = kvsrc + (long)blk * ldkv; wt = wkv; o = kvout + (long)blk * 512; N = 512; }
  float ss = 0.f;
  for (int i = threadIdx.x; i < N; i += 256) { float v = x[i]; ss += v * v; }
#pragma unroll
  for (int off = 32; off; off >>= 1) ss += __shfl_down(ss, off);
  __shared__ float red[4];
  if ((threadIdx.x & 63) == 0) red[threadIdx.x >> 6] = ss;
  __syncthreads();
  float inv = rsqrtf((red[0] + red[1] + red[2] + red[3]) / N + 1e-6f);
  for (int i = threadIdx.x; i < N; i += 256) o[i] = f2bf(wt[i] * x[i] * inv);
}

// ---------------- flash attention (R12 structure, unchanged) ------------------
__global__ __launch_bounds__(256, 2)
void attn_k(const u16* __restrict__ qb, const u16* __restrict__ kswz,
            const u16* __restrict__ vswz, u16* __restrict__ attnO) {
  int lin = blockIdx.x + 16 * blockIdx.y;  // 0..511
  int xcd = lin & 7;
  int j = lin >> 3;                        // 0..63
  int bh = (xcd << 2) + (j >> 4);          // 4 bh per XCD
  int qt = j & 15;
  int b = bh >> 4, h = bh & 15;
  int tid = threadIdx.x, lane = tid & 63, w = tid >> 6;
  int l15 = lane & 15, quad = lane >> 4;
  int qrow0 = qt * 128 + w * 32;

  __shared__ __align__(16) u16 sK[2][24 * 64 * 8];

  const u16* Kb = kswz + (long)bh * 32 * 12288;
  const u16* Vb = vswz + (long)bh * 32 * 8192;

  bf16x8 qf[2][6];
#pragma unroll
  for (int rg = 0; rg < 2; ++rg) {
    const u16* qp = qb + ((long)(b * S_ + qrow0 + rg * 16 + l15)) * 3072 + h * 192 + quad * 8;
#pragma unroll
    for (int kb = 0; kb < 6; ++kb) qf[rg][kb] = *(const bf16x8*)(qp + kb * 32);
  }

  union { u16 v[8]; bf16x8 b; } ones;
#pragma unroll
  for (int e = 0; e < 8; ++e) ones.v[e] = 0x3F80;  // bf16 1.0

  f32x4 o[2][8] = {};
  f32x4 lacc[2] = {};

#pragma unroll
  for (int i = 0; i < 6; ++i) { int c = tid + i * 256; async16(Kb + c * 8, &sK[0][c * 8]); }

#pragma unroll 1
  for (int kt = 0; kt < 32; ++kt) {
    int cur = kt & 1;
    __syncthreads();
    if (kt < 31) {
      const u16* Kt = Kb + (long)(kt + 1) * 12288;
#pragma unroll
      for (int i = 0; i < 6; ++i) { int c = tid + i * 256; async16(Kt + c * 8, &sK[cur ^ 1][c * 8]); }
    }

    const u16* kbase = sK[cur];
    const u16* Vt = Vb + (long)kt * 8192;

    bf16x8 vf0[8], vf1[8];
#pragma unroll
    for (int f = 0; f < 8; ++f)
      vf0[f] = *(const bf16x8*)(Vt + (f * 64 + lane) * 8);

    // QK^T, swapped operands; db outer (8 independent accumulator chains)
    f32x4 s[2][4] = {};
    __builtin_amdgcn_s_setprio(1);
#pragma unroll
    for (int db = 0; db < 6; ++db) {
      bf16x8 kf[4];
#pragma unroll
      for (int kg = 0; kg < 4; ++kg)
        kf[kg] = *(const bf16x8*)(kbase + ((kg * 6 + db) * 64 + lane) * 8);
#pragma unroll
      for (int kg = 0; kg < 4; ++kg) {
        s[0][kg] = mfma16(kf[kg], qf[0][db], s[0][kg]);
        s[1][kg] = mfma16(kf[kg], qf[1][db], s[1][kg]);
      }
    }
    __builtin_amdgcn_s_setprio(0);

#pragma unroll
    for (int f = 0; f < 8; ++f)
      vf1[f] = *(const bf16x8*)(Vt + ((8 + f) * 64 + lane) * 8);

    bf16x8 pf[2][2];
#pragma unroll
    for (int rg = 0; rg < 2; ++rg) {
#pragma unroll
      for (int kg = 0; kg < 4; ++kg) {
#pragma unroll
        for (int r = 0; r < 4; ++r)
          s[rg][kg][r] = __builtin_amdgcn_exp2f(s[rg][kg][r]);
      }
#pragma unroll
      for (int kq = 0; kq < 2; ++kq) {
        union { unsigned wd[4]; bf16x8 v; } u;
        asm("v_cvt_pk_bf16_f32 %0, %1, %2"
            : "=v"(u.wd[0]) : "v"(s[rg][2 * kq][0]), "v"(s[rg][2 * kq][1]));
        asm("v_cvt_pk_bf16_f32 %0, %1, %2"
            : "=v"(u.wd[1]) : "v"(s[rg][2 * kq][2]), "v"(s[rg][2 * kq][3]));
        asm("v_cvt_pk_bf16_f32 %0, %1, %2"
            : "=v"(u.wd[2]) : "v"(s[rg][2 * kq + 1][0]), "v"(s[rg][2 * kq + 1][1]));
        asm("v_cvt_pk_bf16_f32 %0, %1, %2"
            : "=v"(u.wd[3]) : "v"(s[rg][2 * kq + 1][2]), "v"(s[rg][2 * kq + 1][3]));
        pf[rg][kq] = u.v;
      }
      lacc[rg] = mfma16(pf[rg][0], ones.b, lacc[rg]);
      lacc[rg] = mfma16(pf[rg][1], ones.b, lacc[rg]);
    }

    __builtin_amdgcn_s_setprio(1);
#pragma unroll
    for (int j2 = 0; j2 < 8; ++j2) {
      o[0][j2] = mfma16(pf[0][0], vf0[j2], o[0][j2]);
      o[1][j2] = mfma16(pf[1][0], vf0[j2], o[1][j2]);
    }
#pragma unroll
    for (int j2 = 0; j2 < 8; ++j2) {
      o[0][j2] = mfma16(pf[0][1], vf1[j2], o[0][j2]);
      o[1][j2] = mfma16(pf[1][1], vf1[j2], o[1][j2]);
    }
    __builtin_amdgcn_s_setprio(0);
  }

#pragma unroll
  for (int rg = 0; rg < 2; ++rg) {
    u16* op = attnO + ((long)(b * S_ + qrow0 + rg * 16)) * 2048 + h * 128;
    float invr[4];
#pragma unroll
    for (int r = 0; r < 4; ++r) invr[r] = 1.f / lacc[rg][r];
#pragma unroll
    for (int j2 = 0; j2 < 8; ++j2)
#pragma unroll
      for (int r = 0; r < 4; ++r)
        op[(long)(quad * 4 + r) * 2048 + j2 * 16 + l15] = f2bf(o[rg][j2][r] * invr[r]);
  }
}

extern "C" void kernel_launch(void* const* d_in, const int* in_sizes, int n_in,
                              void* d_out, int out_size, void* d_ws, size_t ws_size,
                              hipStream_t stream) {
  const float* hs      = (const float*)d_in[0];
  const float* cosb    = (const float*)d_in[1];
  const float* sinb    = (const float*)d_in[2];
  const float* q_a_w   = (const float*)d_in[3];
  const float* q_a_ln  = (const float*)d_in[4];
  const float* q_b_w   = (const float*)d_in[5];
  const float* kv_a_w  = (const float*)d_in[6];
  const float* kv_a_ln = (const float*)d_in[7];
  const float* kv_b_w  = (const float*)d_in[8];
  const float* o_w     = (const float*)d_in[9];
  float* out = (float*)d_out;
  (void)in_sizes; (void)n_in; (void)out_size; (void)ws_size;

  char* p = (char*)d_ws;
  auto alloc = [&](size_t b) { char* r = p; p += (b + 255) & ~((size_t)255); return r; };
  u16*   hs_bf  = (u16*)  alloc((size_t)4096 * 2048 * 2);   // 16.8 MB
  u16*   qakvT  = (u16*)  alloc((size_t)2176 * 2048 * 2);   // q_a^T(1536) ++ kv_a^T(640 pad)
  u16*   qbwT   = (u16*)  alloc((size_t)3072 * 1536 * 2);
  u16*   kvbwT  = (u16*)  alloc((size_t)4096 * 512  * 2);
  u16*   owT    = (u16*)  alloc((size_t)2048 * 2048 * 2);
  float* qa_ckv = (float*)alloc((size_t)4096 * 2176 * 4);   // 35.7 MB
  u16*   qan    = (u16*)  alloc((size_t)4096 * 1536 * 2);
  u16*   ckvn   = (u16*)  alloc((size_t)4096 * 512  * 2);
  u16*   kr     = (u16*)  alloc((size_t)4096 * 64   * 2);
  u16*   qbuf   = (u16*)  alloc((size_t)4096 * 3072 * 2);
  u16*   aO     = (u16*)  alloc((size_t)4096 * 2048 * 2);
  // aliases onto dead buffers:
  // kswz: 1024*12288*2 = 25.2 MB <= qa_ckv (35.7 MB, dead after rmsnorm/krope)
  // vswz: 1024*8192*2  = 16.8 MB <= hs_bf (16.8 MB, dead after a-proj GEMM)
  u16* kswz = (u16*)qa_ckv;
  u16* vswz = (u16*)hs_bf;

  // prep: hs cast + q_a/kv_a transposes (inputs of the a-proj GEMM)
  prep_k<<<8448, 256, 0, stream>>>(hs, hs_bf, q_a_w, kv_a_w, qakvT);
  // a-proj GEMM + late weight transposes packed into its tail
  aproj_trans_k<<<11296, 256, 0, stream>>>(hs_bf, qakvT, qa_ckv,
                                           q_b_w, kv_b_w, o_w,
                                           qbwT, kvbwT, owT);
  // rmsnorm (q + kv) + krope in one launch
  rmsnorm2_k<<<8704, 256, 0, stream>>>(qa_ckv, 2176, qa_ckv + 1536, 2176,
                                       q_a_ln, kv_a_ln, qan, ckvn,
                                       cosb, sinb, kr);
  // fused q_b (RoPE + folded softmax scale) + kv_b (swizzle + krfill) GEMMs
  qbkvb_k<<<1792, 256, 0, stream>>>(qan, qbwT, qbuf, cosb, sinb,
                                    ckvn, kvbwT, kswz, vswz, kr);
  attn_k<<<dim3(16, 32), 256, 0, stream>>>(qbuf, kswz, vswz, aO);
  gemm_bt_k<float, false><<<dim3(16, 32), 256, 0, stream>>>(
      aO, owT, out, 2048, 2048, 2048, nullptr, nullptr);
}